// Round 2
// baseline (406.329 us; speedup 1.0000x reference)
//
#include <hip/hip_runtime.h>
#include <stdint.h>

// ImpulseNoise (salt & pepper), bit-exact re-implementation of JAX threefry2x32
// under the jax_threefry_partitionable=True (modern default) code path.
//
// key(42) = (0, 42)
// split:   k_flip = TF(key, (0,0)),  k_salt = TF(key, (0,1))   [fold-like split]
// bits[i] = TF(k, (0, i)).x0 ^ TF(k, (0, i)).x1                [partitionable bits]
// out     = (bits_f < FLIP_T) ? ((bits_s < SALT_T) ? 1.0f : 0.0f) : img
//
// V3: V1/V2 both measure ~1090 dynamic VALU instrs/thread (from VALUBusy
// back-calc) vs ~610 ideal. Force the minimum by hand: each dual-cipher round
// is one inline-asm block of exactly 6 ops (2x add, 2x alignbit w/ inline-const
// shift, 2x xor), chains interleaved for ILP. Key injections stay in C (single
// literal-add each). If this doesn't move time, int-VALU is half-rate and we
// are at the issue roofline -> pivot to salt-hash compaction.

__host__ __device__ constexpr uint32_t rotl32(uint32_t x, int r) {
    return (x << r) | (x >> (32 - r));
}

struct TF2 { uint32_t a, b; };

// Host/constexpr reference threefry — compile-time key derivation only.
__host__ __device__ constexpr TF2 threefry2x32(uint32_t k0, uint32_t k1,
                                               uint32_t x0, uint32_t x1) {
    const uint32_t ks0 = k0;
    const uint32_t ks1 = k1;
    const uint32_t ks2 = k0 ^ k1 ^ 0x1BD11BDAu;
    x0 += ks0; x1 += ks1;
    x0 += x1; x1 = rotl32(x1, 13); x1 ^= x0;
    x0 += x1; x1 = rotl32(x1, 15); x1 ^= x0;
    x0 += x1; x1 = rotl32(x1, 26); x1 ^= x0;
    x0 += x1; x1 = rotl32(x1,  6); x1 ^= x0;
    x0 += ks1; x1 += ks2 + 1u;
    x0 += x1; x1 = rotl32(x1, 17); x1 ^= x0;
    x0 += x1; x1 = rotl32(x1, 29); x1 ^= x0;
    x0 += x1; x1 = rotl32(x1, 16); x1 ^= x0;
    x0 += x1; x1 = rotl32(x1, 24); x1 ^= x0;
    x0 += ks2; x1 += ks0 + 2u;
    x0 += x1; x1 = rotl32(x1, 13); x1 ^= x0;
    x0 += x1; x1 = rotl32(x1, 15); x1 ^= x0;
    x0 += x1; x1 = rotl32(x1, 26); x1 ^= x0;
    x0 += x1; x1 = rotl32(x1,  6); x1 ^= x0;
    x0 += ks0; x1 += ks1 + 3u;
    x0 += x1; x1 = rotl32(x1, 17); x1 ^= x0;
    x0 += x1; x1 = rotl32(x1, 29); x1 ^= x0;
    x0 += x1; x1 = rotl32(x1, 16); x1 ^= x0;
    x0 += x1; x1 = rotl32(x1, 24); x1 ^= x0;
    x0 += ks1; x1 += ks2 + 4u;
    x0 += x1; x1 = rotl32(x1, 13); x1 ^= x0;
    x0 += x1; x1 = rotl32(x1, 15); x1 ^= x0;
    x0 += x1; x1 = rotl32(x1, 26); x1 ^= x0;
    x0 += x1; x1 = rotl32(x1,  6); x1 ^= x0;
    x0 += ks2; x1 += ks0 + 5u;
    return {x0, x1};
}

// Compile-time key derivation: seed 42 -> key (0, 42); fold-like split.
constexpr uint32_t SEED_HI = 0u;
constexpr uint32_t SEED_LO = 42u;
constexpr TF2 KFLIP = threefry2x32(SEED_HI, SEED_LO, 0u, 0u);
constexpr TF2 KSALT = threefry2x32(SEED_HI, SEED_LO, 0u, 1u);

// Integer thresholds (exact, verified absmax=0 in prior rounds):
//   uf = (bits>>9)*2^-23 exactly; uf <= 0.09f  <=>  bits < (floor(0.09f*2^23)+1)<<9
constexpr uint32_t FLIP_T = (((uint32_t)((double)0.09f * 8388608.0)) + 1u) << 9;
//   us <= 0.5f  <=>  bits < 0x80000200
constexpr uint32_t SALT_T = 0x80000200u;

// One dual-cipher threefry round, exactly 6 VALU instructions.
// rotl(x,r) == v_alignbit_b32(x,x,32-r); sh = 32-r is an inline constant
// (all sh in {3,6,8,15,16,17,19,26} are free VOP3 inline consts).
#define R2(sh) asm("v_add_u32 %0, %0, %1\n\t"                      \
                   "v_add_u32 %2, %2, %3\n\t"                      \
                   "v_alignbit_b32 %1, %1, %1, " #sh "\n\t"        \
                   "v_alignbit_b32 %3, %3, %3, " #sh "\n\t"        \
                   "v_xor_b32 %1, %1, %0\n\t"                      \
                   "v_xor_b32 %3, %3, %2"                          \
                   : "+v"(a0), "+v"(a1), "+v"(b0), "+v"(b1));

// Both hashes for counter (0, ctr): bf = flip bits, bs = salt bits.
__device__ __forceinline__ void tf_dual(uint32_t ctr, uint32_t& bf, uint32_t& bs) {
    constexpr uint32_t FA = KFLIP.a, FB = KFLIP.b, FC = FA ^ FB ^ 0x1BD11BDAu;
    constexpr uint32_t SA = KSALT.a, SB = KSALT.b, SC = SA ^ SB ^ 0x1BD11BDAu;
    uint32_t a0 = FA, a1 = ctr + FB;          // x0 = 0+ks0, x1 = ctr+ks1
    uint32_t b0 = SA, b1 = ctr + SB;
    // rounds 1-4, rot {13,15,26,6} -> sh {19,17,6,26}
    R2(19) R2(17) R2(6) R2(26)
    a0 += FB; a1 += FC + 1u;  b0 += SB; b1 += SC + 1u;
    // rounds 5-8, rot {17,29,16,24} -> sh {15,3,16,8}
    R2(15) R2(3) R2(16) R2(8)
    a0 += FC; a1 += FA + 2u;  b0 += SC; b1 += SA + 2u;
    // rounds 9-12 (A)
    R2(19) R2(17) R2(6) R2(26)
    a0 += FA; a1 += FB + 3u;  b0 += SA; b1 += SB + 3u;
    // rounds 13-16 (B)
    R2(15) R2(3) R2(16) R2(8)
    a0 += FB; a1 += FC + 4u;  b0 += SB; b1 += SC + 4u;
    // rounds 17-20 (A)
    R2(19) R2(17) R2(6) R2(26)
    a0 += FC; a1 += FA + 5u;  b0 += SC; b1 += SA + 5u;
    bf = a0 ^ a1;
    bs = b0 ^ b1;
}

__global__ __launch_bounds__(256)
void ImpulseNoise_32040456028513_kernel(const float4* __restrict__ in,
                                        float4* __restrict__ out,
                                        unsigned n4) {
    unsigned tid = blockIdx.x * blockDim.x + threadIdx.x;
    if (tid >= n4) return;

    float4 v = in[tid];
    float r[4] = {v.x, v.y, v.z, v.w};
    const uint32_t base = tid << 2;

#pragma unroll
    for (int j = 0; j < 4; ++j) {
        uint32_t bits_f, bits_s;
        tf_dual(base + (uint32_t)j, bits_f, bits_s);
        float sp = (bits_s < SALT_T) ? 1.0f : 0.0f;
        r[j] = (bits_f < FLIP_T) ? sp : r[j];
    }

    out[tid] = make_float4(r[0], r[1], r[2], r[3]);
}

extern "C" void kernel_launch(void* const* d_in, const int* in_sizes, int n_in,
                              void* d_out, int out_size, void* d_ws, size_t ws_size,
                              hipStream_t stream) {
    const float4* in = (const float4*)d_in[0];
    float4* out = (float4*)d_out;
    unsigned n = (unsigned)in_sizes[0];   // 64*3*512*512 = 50331648, divisible by 4
    unsigned n4 = n >> 2;
    unsigned blocks = (n4 + 255u) / 256u;
    ImpulseNoise_32040456028513_kernel<<<blocks, 256, 0, stream>>>(in, out, n4);
}

// Round 3
// 349.294 us; speedup vs baseline: 1.1633x; 1.1633x over previous
//
#include <hip/hip_runtime.h>
#include <stdint.h>

// ImpulseNoise (salt & pepper), bit-exact re-implementation of JAX threefry2x32
// under the jax_threefry_partitionable=True (modern default) code path.
//
// key(42) = (0, 42)
// split:   k_flip = TF(key, (0,0)),  k_salt = TF(key, (0,1))   [fold-like split]
// bits[i] = TF(k, (0, i)).x0 ^ TF(k, (0, i)).x1                [partitionable bits]
// out     = (bits_f < FLIP_T) ? ((bits_s < SALT_T) ? 1.0f : 0.0f) : img
//
// V4: VALU-issue-bound (V1/V2/V3: three different codegens, all ~180-200us,
// VALUBusy ~100%). Only lever left is issued-instruction count. Salt hashes
// are consumed by only 9% of elements -> wave-level compaction: a wave owns
// 256 elements, E[flipped]=23 +- 4.6, so ONE 64-lane salt batch almost always
// suffices (batch loop handles any count up to 256 exactly).
//   - 4 flip hashes/thread (unavoidable), ballot per element slot
//   - rank r = cum_j + mbcnt(B_j)  (unique across wave)
//   - flipped owners push counter to LDS slot[rank]   (wave-local, no barrier)
//   - worker lane L hashes slot[batch+L] with salt key; ballot -> uniform
//     64-bit salt mask; owner extracts bit (rank-batch)
// ~430 VALU/thread vs ~615 -> predict ~0.70x time.

__host__ __device__ constexpr uint32_t rotl32(uint32_t x, int r) {
    return (x << r) | (x >> (32 - r));
}

struct TF2 { uint32_t a, b; };

// Host/constexpr reference threefry — compile-time key derivation only.
__host__ __device__ constexpr TF2 threefry2x32(uint32_t k0, uint32_t k1,
                                               uint32_t x0, uint32_t x1) {
    const uint32_t ks0 = k0;
    const uint32_t ks1 = k1;
    const uint32_t ks2 = k0 ^ k1 ^ 0x1BD11BDAu;
    x0 += ks0; x1 += ks1;
    x0 += x1; x1 = rotl32(x1, 13); x1 ^= x0;
    x0 += x1; x1 = rotl32(x1, 15); x1 ^= x0;
    x0 += x1; x1 = rotl32(x1, 26); x1 ^= x0;
    x0 += x1; x1 = rotl32(x1,  6); x1 ^= x0;
    x0 += ks1; x1 += ks2 + 1u;
    x0 += x1; x1 = rotl32(x1, 17); x1 ^= x0;
    x0 += x1; x1 = rotl32(x1, 29); x1 ^= x0;
    x0 += x1; x1 = rotl32(x1, 16); x1 ^= x0;
    x0 += x1; x1 = rotl32(x1, 24); x1 ^= x0;
    x0 += ks2; x1 += ks0 + 2u;
    x0 += x1; x1 = rotl32(x1, 13); x1 ^= x0;
    x0 += x1; x1 = rotl32(x1, 15); x1 ^= x0;
    x0 += x1; x1 = rotl32(x1, 26); x1 ^= x0;
    x0 += x1; x1 = rotl32(x1,  6); x1 ^= x0;
    x0 += ks0; x1 += ks1 + 3u;
    x0 += x1; x1 = rotl32(x1, 17); x1 ^= x0;
    x0 += x1; x1 = rotl32(x1, 29); x1 ^= x0;
    x0 += x1; x1 = rotl32(x1, 16); x1 ^= x0;
    x0 += x1; x1 = rotl32(x1, 24); x1 ^= x0;
    x0 += ks1; x1 += ks2 + 4u;
    x0 += x1; x1 = rotl32(x1, 13); x1 ^= x0;
    x0 += x1; x1 = rotl32(x1, 15); x1 ^= x0;
    x0 += x1; x1 = rotl32(x1, 26); x1 ^= x0;
    x0 += x1; x1 = rotl32(x1,  6); x1 ^= x0;
    x0 += ks2; x1 += ks0 + 5u;
    return {x0, x1};
}

// Compile-time key derivation: seed 42 -> key (0, 42); fold-like split.
constexpr uint32_t SEED_HI = 0u;
constexpr uint32_t SEED_LO = 42u;
constexpr TF2 KFLIP = threefry2x32(SEED_HI, SEED_LO, 0u, 0u);
constexpr TF2 KSALT = threefry2x32(SEED_HI, SEED_LO, 0u, 1u);

// Integer thresholds (exact; verified absmax=0 in V2/V3):
constexpr uint32_t FLIP_T = (((uint32_t)((double)0.09f * 8388608.0)) + 1u) << 9;
constexpr uint32_t SALT_T = 0x80000200u;

// Single-instruction rotate (verified bit-exact in V2/V3).
__device__ __forceinline__ uint32_t rotl_d(uint32_t x, int r) {
    return __builtin_amdgcn_alignbit(x, x, 32u - (uint32_t)r);
}

#define TFR(rot) { x0 += x1; x1 = rotl_d(x1, rot); x1 ^= x0; }

// Threefry with compile-time key; returns x0 ^ x1 (partitionable bits word).
template <uint32_t K0, uint32_t K1>
__device__ __forceinline__ uint32_t tf_bits(uint32_t ctr) {
    constexpr uint32_t K2 = K0 ^ K1 ^ 0x1BD11BDAu;
    uint32_t x0 = K0;            // 0 + ks0
    uint32_t x1 = ctr + K1;
    TFR(13) TFR(15) TFR(26) TFR(6)
    x0 += K1; x1 += K2 + 1u;
    TFR(17) TFR(29) TFR(16) TFR(24)
    x0 += K2; x1 += K0 + 2u;
    TFR(13) TFR(15) TFR(26) TFR(6)
    x0 += K0; x1 += K1 + 3u;
    TFR(17) TFR(29) TFR(16) TFR(24)
    x0 += K1; x1 += K2 + 4u;
    TFR(13) TFR(15) TFR(26) TFR(6)
    x0 += K2; x1 += K0 + 5u;
    return x0 ^ x1;
}

// Count of set bits of m strictly below this lane.
__device__ __forceinline__ uint32_t mbcnt64(uint64_t m) {
    return __builtin_amdgcn_mbcnt_hi((uint32_t)(m >> 32),
           __builtin_amdgcn_mbcnt_lo((uint32_t)m, 0u));
}

__global__ __launch_bounds__(256)
void ImpulseNoise_32040456028513_kernel(const float4* __restrict__ in,
                                        float4* __restrict__ out,
                                        unsigned n4) {
    // Per-wave compaction scratch: up to 256 flipped counters per wave.
    __shared__ uint32_t slots[1024];            // 4 waves * 256 slots
    const unsigned t = blockIdx.x * 256u + threadIdx.x;
    // n4 = 12,582,912 = 49152 * 256 exactly: this guard never diverges a wave,
    // so the wave-collective ballots below are always fully converged.
    if (t >= n4) return;

    const unsigned lane = threadIdx.x & 63u;
    uint32_t* ws = &slots[(threadIdx.x >> 6) << 8];

    const float4 v = in[t];
    const uint32_t base = t << 2;

    // ---- 4 flip hashes (unavoidable; compiler interleaves the 4 chains) ----
    const uint32_t f0 = tf_bits<KFLIP.a, KFLIP.b>(base);
    const uint32_t f1 = tf_bits<KFLIP.a, KFLIP.b>(base + 1u);
    const uint32_t f2 = tf_bits<KFLIP.a, KFLIP.b>(base + 2u);
    const uint32_t f3 = tf_bits<KFLIP.a, KFLIP.b>(base + 3u);
    const bool flip0 = f0 < FLIP_T;
    const bool flip1 = f1 < FLIP_T;
    const bool flip2 = f2 < FLIP_T;
    const bool flip3 = f3 < FLIP_T;

    // ---- wave-level ranks: unique rank per flipped element ----
    const uint64_t B0 = __ballot(flip0);
    const uint64_t B1 = __ballot(flip1);
    const uint64_t B2 = __ballot(flip2);
    const uint64_t B3 = __ballot(flip3);

    const uint32_t cum1 = (uint32_t)__popcll(B0);
    const uint32_t cum2 = cum1 + (uint32_t)__popcll(B1);
    const uint32_t cum3 = cum2 + (uint32_t)__popcll(B2);
    const uint32_t total = cum3 + (uint32_t)__popcll(B3);

    const uint32_t r0 = mbcnt64(B0);            // ranks; for non-flipped j the
    const uint32_t r1 = cum1 + mbcnt64(B1);     // value aliases a real rank but
    const uint32_t r2 = cum2 + mbcnt64(B2);     // s_j is then never consumed.
    const uint32_t r3 = cum3 + mbcnt64(B3);

    // ---- owners push counters of flipped elements to their rank slot ----
    if (flip0) ws[r0] = base;
    if (flip1) ws[r1] = base + 1u;
    if (flip2) ws[r2] = base + 2u;
    if (flip3) ws[r3] = base + 3u;
    __threadfence_block();   // order LDS writes before wave-local reads

    // ---- workers: one salt-hash batch per 64 flipped elements (E[total]=23,
    //      so almost always exactly one iteration; exact for any total) ----
    uint32_t s0 = 0u, s1 = 0u, s2 = 0u, s3 = 0u;
    for (uint32_t b = 0; b < total; b += 64u) {
        const uint32_t ctr = ws[b + lane];                 // stride-1: no conflicts
        const uint32_t h = tf_bits<KSALT.a, KSALT.b>(ctr); // garbage lanes harmless
        const uint64_t S = __ballot(h < SALT_T);           // uniform salt-bit mask
        const uint32_t d0 = r0 - b, d1 = r1 - b, d2 = r2 - b, d3 = r3 - b;
        if (d0 < 64u) s0 = (uint32_t)(S >> d0) & 1u;
        if (d1 < 64u) s1 = (uint32_t)(S >> d1) & 1u;
        if (d2 < 64u) s2 = (uint32_t)(S >> d2) & 1u;
        if (d3 < 64u) s3 = (uint32_t)(S >> d3) & 1u;
    }

    // ---- combine: salt bit -> {0.0f, 1.0f} exactly via int->float convert ----
    float4 o;
    o.x = flip0 ? (float)s0 : v.x;
    o.y = flip1 ? (float)s1 : v.y;
    o.z = flip2 ? (float)s2 : v.z;
    o.w = flip3 ? (float)s3 : v.w;
    out[t] = o;
}

extern "C" void kernel_launch(void* const* d_in, const int* in_sizes, int n_in,
                              void* d_out, int out_size, void* d_ws, size_t ws_size,
                              hipStream_t stream) {
    const float4* in = (const float4*)d_in[0];
    float4* out = (float4*)d_out;
    unsigned n = (unsigned)in_sizes[0];   // 64*3*512*512 = 50331648, divisible by 4
    unsigned n4 = n >> 2;                 // 12,582,912 = 49152 blocks * 256
    unsigned blocks = (n4 + 255u) / 256u;
    ImpulseNoise_32040456028513_kernel<<<blocks, 256, 0, stream>>>(in, out, n4);
}

// Round 4
// 332.553 us; speedup vs baseline: 1.2218x; 1.0503x over previous
//
#include <hip/hip_runtime.h>
#include <stdint.h>

// ImpulseNoise (salt & pepper), bit-exact re-implementation of JAX threefry2x32
// under the jax_threefry_partitionable=True (modern default) code path.
//
// key(42) = (0, 42)
// split:   k_flip = TF(key, (0,0)),  k_salt = TF(key, (0,1))   [fold-like split]
// bits[i] = TF(k, (0, i)).x0 ^ TF(k, (0, i)).x1                [partitionable bits]
// out     = (bits_f < FLIP_T) ? ((bits_s < SALT_T) ? 1.0f : 0.0f) : img
//
// V5 (V4 confirmed the model: time ~ issued VALU instrs; 199->139us = 0.70x
// as predicted). Per-64-elements cost in V4: 73 flip-hash (irreducible) +
// 18 salt + 15 overhead. V5 cuts the non-hash terms:
//  - 8 elements/thread (512/wave): E[flipped/wave]=46, still ONE 64-lane salt
//    batch -> salt cost halves per element (loop still exact for any count).
//  - LDS write-back: workers overwrite slot with final float bits; owners read
//    ws[rank] after the loop. Kills the 64-bit shift/mask extract chain + cvt.
//  - Rank/slot assignment is order-free (any bijection works), ballots double
//    as the flip compares, popcounts ride the SALU pipe.
// ~87.5 wave-instrs / 64 elements vs 106 -> predict ~ -15%.

__host__ __device__ constexpr uint32_t rotl32(uint32_t x, int r) {
    return (x << r) | (x >> (32 - r));
}

struct TF2 { uint32_t a, b; };

// Host/constexpr reference threefry — compile-time key derivation only.
__host__ __device__ constexpr TF2 threefry2x32(uint32_t k0, uint32_t k1,
                                               uint32_t x0, uint32_t x1) {
    const uint32_t ks0 = k0;
    const uint32_t ks1 = k1;
    const uint32_t ks2 = k0 ^ k1 ^ 0x1BD11BDAu;
    x0 += ks0; x1 += ks1;
    x0 += x1; x1 = rotl32(x1, 13); x1 ^= x0;
    x0 += x1; x1 = rotl32(x1, 15); x1 ^= x0;
    x0 += x1; x1 = rotl32(x1, 26); x1 ^= x0;
    x0 += x1; x1 = rotl32(x1,  6); x1 ^= x0;
    x0 += ks1; x1 += ks2 + 1u;
    x0 += x1; x1 = rotl32(x1, 17); x1 ^= x0;
    x0 += x1; x1 = rotl32(x1, 29); x1 ^= x0;
    x0 += x1; x1 = rotl32(x1, 16); x1 ^= x0;
    x0 += x1; x1 = rotl32(x1, 24); x1 ^= x0;
    x0 += ks2; x1 += ks0 + 2u;
    x0 += x1; x1 = rotl32(x1, 13); x1 ^= x0;
    x0 += x1; x1 = rotl32(x1, 15); x1 ^= x0;
    x0 += x1; x1 = rotl32(x1, 26); x1 ^= x0;
    x0 += x1; x1 = rotl32(x1,  6); x1 ^= x0;
    x0 += ks0; x1 += ks1 + 3u;
    x0 += x1; x1 = rotl32(x1, 17); x1 ^= x0;
    x0 += x1; x1 = rotl32(x1, 29); x1 ^= x0;
    x0 += x1; x1 = rotl32(x1, 16); x1 ^= x0;
    x0 += x1; x1 = rotl32(x1, 24); x1 ^= x0;
    x0 += ks1; x1 += ks2 + 4u;
    x0 += x1; x1 = rotl32(x1, 13); x1 ^= x0;
    x0 += x1; x1 = rotl32(x1, 15); x1 ^= x0;
    x0 += x1; x1 = rotl32(x1, 26); x1 ^= x0;
    x0 += x1; x1 = rotl32(x1,  6); x1 ^= x0;
    x0 += ks2; x1 += ks0 + 5u;
    return {x0, x1};
}

// Compile-time key derivation: seed 42 -> key (0, 42); fold-like split.
constexpr uint32_t SEED_HI = 0u;
constexpr uint32_t SEED_LO = 42u;
constexpr TF2 KFLIP = threefry2x32(SEED_HI, SEED_LO, 0u, 0u);
constexpr TF2 KSALT = threefry2x32(SEED_HI, SEED_LO, 0u, 1u);

// Integer thresholds (exact; absmax=0 verified in V2/V3/V4):
constexpr uint32_t FLIP_T = (((uint32_t)((double)0.09f * 8388608.0)) + 1u) << 9;
constexpr uint32_t SALT_T = 0x80000200u;

// Single-instruction rotate (bit-exact, verified).
__device__ __forceinline__ uint32_t rotl_d(uint32_t x, int r) {
    return __builtin_amdgcn_alignbit(x, x, 32u - (uint32_t)r);
}

#define TFR(rot) { x0 += x1; x1 = rotl_d(x1, rot); x1 ^= x0; }

// Threefry with compile-time key; returns x0 ^ x1 (partitionable bits word).
template <uint32_t K0, uint32_t K1>
__device__ __forceinline__ uint32_t tf_bits(uint32_t ctr) {
    constexpr uint32_t K2 = K0 ^ K1 ^ 0x1BD11BDAu;
    uint32_t x0 = K0;            // 0 + ks0
    uint32_t x1 = ctr + K1;
    TFR(13) TFR(15) TFR(26) TFR(6)
    x0 += K1; x1 += K2 + 1u;
    TFR(17) TFR(29) TFR(16) TFR(24)
    x0 += K2; x1 += K0 + 2u;
    TFR(13) TFR(15) TFR(26) TFR(6)
    x0 += K0; x1 += K1 + 3u;
    TFR(17) TFR(29) TFR(16) TFR(24)
    x0 += K1; x1 += K2 + 4u;
    TFR(13) TFR(15) TFR(26) TFR(6)
    x0 += K2; x1 += K0 + 5u;
    return x0 ^ x1;
}

// Count of set bits of m strictly below this lane.
__device__ __forceinline__ uint32_t mbcnt64(uint64_t m) {
    return __builtin_amdgcn_mbcnt_hi((uint32_t)(m >> 32),
           __builtin_amdgcn_mbcnt_lo((uint32_t)m, 0u));
}

__global__ __launch_bounds__(256)
void ImpulseNoise_32040456028513_kernel(const float4* __restrict__ in,
                                        float4* __restrict__ out,
                                        unsigned nthreads) {
    // Per-wave compaction scratch: worst case all 512 elements flip.
    __shared__ uint32_t slots[4][512];                  // 8 KiB / block
    const unsigned t = blockIdx.x * 256u + threadIdx.x;
    // nthreads = 6,291,456 = 24576 * 256 exactly: guard never splits a wave,
    // so all wave collectives below are fully converged.
    if (t >= nthreads) return;

    const unsigned lane = threadIdx.x & 63u;
    uint32_t* ws = slots[threadIdx.x >> 6];

    // Wave owns 512 consecutive elements = 128 float4s; lane reads float4
    // wbase+lane and wbase+64+lane -> both loads fully coalesced.
    const unsigned w = t >> 6;                          // global wave id
    const unsigned i0 = (w << 7) + lane;                // float4 index A
    const unsigned i1 = i0 + 64u;                       // float4 index B
    const float4 va = in[i0];
    const float4 vb = in[i1];
    const uint32_t cb0 = i0 << 2;                       // element counters
    const uint32_t cb1 = i1 << 2;

    // ---- 8 flip hashes (one per element; structurally irreducible) ----
    uint32_t f[8];
#pragma unroll
    for (int j = 0; j < 4; ++j) f[j]     = tf_bits<KFLIP.a, KFLIP.b>(cb0 + (uint32_t)j);
#pragma unroll
    for (int j = 0; j < 4; ++j) f[4 + j] = tf_bits<KFLIP.a, KFLIP.b>(cb1 + (uint32_t)j);

    // ---- unique rank per flipped element; owners push counters to slots ----
    // (slot order is arbitrary: any wave-level bijection works, since owners
    //  read back by rank after workers overwrite slots with the result bits)
    bool flip[8];
    uint32_t r[8];
    uint32_t cum = 0u;
#pragma unroll
    for (int k = 0; k < 8; ++k) {
        flip[k] = f[k] < FLIP_T;
        const uint64_t B = __ballot(flip[k]);
        r[k] = cum + mbcnt64(B);
        cum += (uint32_t)__popcll(B);                   // s_bcnt1: SALU pipe
        if (flip[k]) ws[r[k]] = ((k < 4) ? cb0 : cb1) + (uint32_t)(k & 3);
    }
    __threadfence_block();   // order owner writes before worker reads

    // ---- workers: one salt batch per 64 flipped (E[cum]=46 -> ~always 1
    //      iteration; exact for any cum<=512). Slot is overwritten in place
    //      with the final float bit pattern. ----
    for (uint32_t b = 0; b < cum; b += 64u) {
        const uint32_t ctr = ws[b + lane];              // stride-1, conflict-free
        const uint32_t h = tf_bits<KSALT.a, KSALT.b>(ctr);
        ws[b + lane] = (h < SALT_T) ? 0x3F800000u : 0u; // 1.0f : 0.0f
    }
    __threadfence_block();   // order worker writes before owner reads

    // ---- owners pull their float directly; slots >= cum are garbage but
    //      only read when flip[k] is false-path-discarded by cndmask ----
    float s[8];
#pragma unroll
    for (int k = 0; k < 8; ++k) s[k] = __uint_as_float(ws[r[k]]);

    float4 oa, ob;
    oa.x = flip[0] ? s[0] : va.x;
    oa.y = flip[1] ? s[1] : va.y;
    oa.z = flip[2] ? s[2] : va.z;
    oa.w = flip[3] ? s[3] : va.w;
    ob.x = flip[4] ? s[4] : vb.x;
    ob.y = flip[5] ? s[5] : vb.y;
    ob.z = flip[6] ? s[6] : vb.z;
    ob.w = flip[7] ? s[7] : vb.w;
    out[i0] = oa;
    out[i1] = ob;
}

extern "C" void kernel_launch(void* const* d_in, const int* in_sizes, int n_in,
                              void* d_out, int out_size, void* d_ws, size_t ws_size,
                              hipStream_t stream) {
    const float4* in = (const float4*)d_in[0];
    float4* out = (float4*)d_out;
    unsigned n = (unsigned)in_sizes[0];   // 64*3*512*512 = 50331648, divisible by 8
    unsigned nthreads = n >> 3;           // 8 elements per thread
    unsigned blocks = (nthreads + 255u) / 256u;
    ImpulseNoise_32040456028513_kernel<<<blocks, 256, 0, stream>>>(in, out, nthreads);
}